// Round 3
// baseline (42.512 us; speedup 1.0000x reference)
//
#include <hip/hip_runtime.h>
#include <hip/hip_cooperative_groups.h>

namespace cg = cooperative_groups;

// LEOBlock collapsed: codes[c] = [emb(cmean[c]), embbar] @ W1^T @ W2^T @ W3^T,
// broadcast over 50 shots.  embbar = mean_c emb[c] is the ONLY cross-block
// dependency -> single cooperative kernel with one grid.sync().
#define FEAT 640
#define LAT 64
#define REL 128      // 2*LAT
#define NWAY 20
#define KSHOT 50
#define OUT_FLOATS (NWAY * KSHOT * REL)   // 128000

__global__ __launch_bounds__(1024) void leo_fused(const float* __restrict__ support,
                                                  const float* __restrict__ W_enc,
                                                  const float* __restrict__ W1,
                                                  const float* __restrict__ W2,
                                                  const float* __restrict__ W3,
                                                  float* out,
                                                  float* emb_ws,   // [NWAY][LAT]
                                                  int sync2) {     // 1 iff emb_ws aliases out tail
    __shared__ float4 s_part[6][160];   // 15360 B: per-rowgroup partial col sums
    __shared__ float  s_cm[FEAT];       // 2560 B: class mean
    __shared__ float  s_v[4][REL];      // 2048 B: cat / v1 / v2 / codes

    const int c = blockIdx.x;           // class 0..19
    const int t = threadIdx.x;

    // ---- phase 1a: class mean of support rows [c*50, c*50+50) ----
    if (t < 960) {
        const int col4 = t % 160;       // float4 column
        const int rg   = t / 160;       // row group 0..5
        const float4* base = (const float4*)(support + (size_t)c * KSHOT * FEAT) + col4;
        float4 a = make_float4(0.f, 0.f, 0.f, 0.f);
        for (int r = rg; r < KSHOT; r += 6) {       // coalesced 16 B/lane
            const float4 v = base[(size_t)r * (FEAT / 4)];
            a.x += v.x; a.y += v.y; a.z += v.z; a.w += v.w;
        }
        s_part[rg][col4] = a;
    }
    __syncthreads();
    if (t < 160) {
        float4 a = s_part[0][t];
#pragma unroll
        for (int g = 1; g < 6; ++g) {
            const float4 v = s_part[g][t];
            a.x += v.x; a.y += v.y; a.z += v.z; a.w += v.w;
        }
        const float inv = 1.0f / KSHOT;
        ((float4*)s_cm)[t] = make_float4(a.x * inv, a.y * inv, a.z * inv, a.w * inv);
    }
    __syncthreads();

    // ---- phase 1b: emb[c][l] = cmean[c] . W_enc[l]; 16 threads/output ----
    {
        const int l = t >> 4, p = t & 15;
        const float4* wr = (const float4*)(W_enc + l * FEAT + p * 40);
        const float4* xv = (const float4*)(s_cm + p * 40);
        float a0 = 0.f, a1 = 0.f, a2 = 0.f, a3 = 0.f;
#pragma unroll
        for (int i = 0; i < 10; ++i) {
            const float4 w = wr[i], x = xv[i];
            a0 += w.x * x.x; a1 += w.y * x.y; a2 += w.z * x.z; a3 += w.w * x.w;
        }
        float acc = (a0 + a1) + (a2 + a3);
        acc += __shfl_xor(acc, 8, 16);
        acc += __shfl_xor(acc, 4, 16);
        acc += __shfl_xor(acc, 2, 16);
        acc += __shfl_xor(acc, 1, 16);
        if (p == 0) emb_ws[c * LAT + l] = acc;
    }
    __threadfence();
    cg::this_grid().sync();

    // ---- phase 2: cat = [emb[c], embbar] ----
    if (t < LAT) {
        s_v[0][t] = emb_ws[c * LAT + t];
    } else if (t < 2 * LAT) {
        const int l = t - LAT;
        float s = 0.f;
#pragma unroll
        for (int cc = 0; cc < NWAY; ++cc) s += emb_ws[cc * LAT + l];
        s_v[0][LAT + l] = s * (1.0f / NWAY);
    }
    __syncthreads();
    if (sync2) cg::this_grid().sync();  // fallback: emb lives in out tail — all
                                        // blocks must finish reading before any
                                        // out writes below.

    // ---- three 128x128 bias-free linears; 8 threads/output ----
    auto stage = [&](const float* __restrict__ W, const float* sin_, float* sout) {
        const int r = t >> 3, p = t & 7;
        const float4* wr = (const float4*)(W + r * REL + p * 16);
        const float4* xv = (const float4*)(sin_ + p * 16);
        float a0 = 0.f, a1 = 0.f, a2 = 0.f, a3 = 0.f;
#pragma unroll
        for (int i = 0; i < 4; ++i) {
            const float4 w = wr[i], x = xv[i];
            a0 += w.x * x.x; a1 += w.y * x.y; a2 += w.z * x.z; a3 += w.w * x.w;
        }
        float acc = (a0 + a1) + (a2 + a3);
        acc += __shfl_xor(acc, 4, 8);
        acc += __shfl_xor(acc, 2, 8);
        acc += __shfl_xor(acc, 1, 8);
        if (p == 0) sout[r] = acc;
        __syncthreads();
    };
    stage(W1, s_v[0], s_v[1]);
    stage(W2, s_v[1], s_v[2]);
    stage(W3, s_v[2], s_v[3]);

    // ---- broadcast codes[c] over 50 shots (float4, coalesced) ----
    const float4* codes4 = (const float4*)s_v[3];
    float4* out4 = (float4*)out + (size_t)c * (KSHOT * REL / 4);
    for (int i = t; i < KSHOT * REL / 4; i += 1024)
        out4[i] = codes4[i & 31];
}

// ---------------------------------------------------------------------------
extern "C" void kernel_launch(void* const* d_in, const int* in_sizes, int n_in,
                              void* d_out, int out_size, void* d_ws, size_t ws_size,
                              hipStream_t stream) {
    const float* support = (const float*)d_in[0];   // [1000][640]
    const float* W_enc   = (const float*)d_in[1];   // [64][640]
    const float* W1      = (const float*)d_in[2];   // [128][128]
    const float* W2      = (const float*)d_in[3];   // [128][128]
    const float* W3      = (const float*)d_in[4];   // [128][128]
    float* out = (float*)d_out;                     // [20][50][128]

    float* emb_ws;
    int sync2;
    if (ws_size >= (size_t)(NWAY * LAT) * sizeof(float)) {
        emb_ws = (float*)d_ws;              sync2 = 0;
    } else {
        // stash emb in the last 1280 floats of out (inside class 19's slice);
        // a second grid.sync() orders all reads before any out writes.
        emb_ws = out + OUT_FLOATS - NWAY * LAT;  sync2 = 1;
    }

    void* args[] = {(void*)&support, (void*)&W_enc, (void*)&W1, (void*)&W2,
                    (void*)&W3, (void*)&out, (void*)&emb_ws, (void*)&sync2};
    hipLaunchCooperativeKernel((void*)leo_fused, dim3(NWAY), dim3(1024),
                               args, 0, stream);
}

// Round 4
// 15.494 us; speedup vs baseline: 2.7437x; 2.7437x over previous
//
#include <hip/hip_runtime.h>

// LEOBlock collapsed: codes[c] = [emb(cmean[c]), embbar] @ W1^T @ W2^T @ W3^T,
// broadcast over 50 shots.  emb (20x64) is the ONLY cross-block dependency:
//   K_A: per-class mean of support + encoder matvec  -> emb_ws
//   K_B: embbar (recomputed per block from emb_ws) + 3 linears + broadcast out
#define FEAT 640
#define LAT 64
#define REL 128      // 2*LAT
#define NWAY 20
#define KSHOT 50
#define OUT_FLOATS (NWAY * KSHOT * REL)   // 128000

// ---------------------------------------------------------------------------
// K_A: cmean[c] = mean_k support[c*50+k]; emb[c][l] = cmean[c] . W_enc[l]
// 20 blocks x 1024 threads.
// ---------------------------------------------------------------------------
__global__ __launch_bounds__(1024) void leo_emb(const float* __restrict__ support,
                                                const float* __restrict__ W_enc,
                                                float* emb_ws) {
    __shared__ float4 s_part[6][160];   // per-rowgroup partial column sums
    __shared__ float  s_cm[FEAT];

    const int c = blockIdx.x, t = threadIdx.x;

    // class mean: 6 row-groups x 160 float4 columns, coalesced 16 B/lane
    if (t < 960) {
        const int col4 = t % 160, rg = t / 160;
        const float4* base = (const float4*)(support + (size_t)c * KSHOT * FEAT) + col4;
        float4 a = make_float4(0.f, 0.f, 0.f, 0.f);
        for (int r = rg; r < KSHOT; r += 6) {
            const float4 v = base[(size_t)r * (FEAT / 4)];
            a.x += v.x; a.y += v.y; a.z += v.z; a.w += v.w;
        }
        s_part[rg][col4] = a;
    }
    __syncthreads();
    if (t < 160) {
        float4 a = s_part[0][t];
#pragma unroll
        for (int g = 1; g < 6; ++g) {
            const float4 v = s_part[g][t];
            a.x += v.x; a.y += v.y; a.z += v.z; a.w += v.w;
        }
        const float inv = 1.0f / KSHOT;
        ((float4*)s_cm)[t] = make_float4(a.x * inv, a.y * inv, a.z * inv, a.w * inv);
    }
    __syncthreads();

    // encoder: 16 threads per output l, 10 float4 MACs each, shfl-xor reduce
    const int l = t >> 4, p = t & 15;
    const float4* wr = (const float4*)(W_enc + l * FEAT + p * 40);
    const float4* xv = (const float4*)(s_cm + p * 40);
    float a0 = 0.f, a1 = 0.f, a2 = 0.f, a3 = 0.f;
#pragma unroll
    for (int i = 0; i < 10; ++i) {
        const float4 w = wr[i], x = xv[i];
        a0 += w.x * x.x; a1 += w.y * x.y; a2 += w.z * x.z; a3 += w.w * x.w;
    }
    float acc = (a0 + a1) + (a2 + a3);
    acc += __shfl_xor(acc, 8, 16);
    acc += __shfl_xor(acc, 4, 16);
    acc += __shfl_xor(acc, 2, 16);
    acc += __shfl_xor(acc, 1, 16);
    if (p == 0) emb_ws[c * LAT + l] = acc;
}

// ---------------------------------------------------------------------------
// K_B: per class c: cat = [emb[c], mean_c emb]; v1=cat@W1^T; v2=v1@W2^T;
// codes=v2@W3^T; out[c][k][:]=codes for k<50.  20 blocks x 1024 threads.
// skip_tail=1 (fallback only): emb_ws aliases the last 1280 floats of out
// (class-19 rows 40..49); block 19 then skips those rows and a patch kernel
// fills them afterwards -> no inter-block read/write race.
// ---------------------------------------------------------------------------
__global__ __launch_bounds__(1024) void leo_codes(const float* emb_ws,
                                                  const float* __restrict__ W1,
                                                  const float* __restrict__ W2,
                                                  const float* __restrict__ W3,
                                                  float* out, int skip_tail) {
    __shared__ float s_emb[NWAY * LAT];   // 5120 B
    __shared__ float s_v[4][REL];         // cat / v1 / v2 / codes

    const int c = blockIdx.x, t = threadIdx.x;

    // stage all emb rows (coalesced; wave-broadcast source)
    for (int i = t; i < NWAY * LAT; i += 1024) s_emb[i] = emb_ws[i];
    __syncthreads();

    if (t < LAT) {           // embbar -> right half
        float s = 0.f;
#pragma unroll
        for (int cc = 0; cc < NWAY; ++cc) s += s_emb[cc * LAT + t];
        s_v[0][LAT + t] = s * (1.0f / NWAY);
    } else if (t < 2 * LAT) { // own emb -> left half
        s_v[0][t - LAT] = s_emb[c * LAT + (t - LAT)];
    }
    __syncthreads();

    // three bias-free 128x128 linears: 8 threads/output, 4 float4 MACs each
    auto stage = [&](const float* __restrict__ W, const float* sin_, float* sout) {
        const int r = t >> 3, p = t & 7;
        const float4* wr = (const float4*)(W + r * REL + p * 16);
        const float4* xv = (const float4*)(sin_ + p * 16);
        float a0 = 0.f, a1 = 0.f, a2 = 0.f, a3 = 0.f;
#pragma unroll
        for (int i = 0; i < 4; ++i) {
            const float4 w = wr[i], x = xv[i];
            a0 += w.x * x.x; a1 += w.y * x.y; a2 += w.z * x.z; a3 += w.w * x.w;
        }
        float acc = (a0 + a1) + (a2 + a3);
        acc += __shfl_xor(acc, 4, 8);
        acc += __shfl_xor(acc, 2, 8);
        acc += __shfl_xor(acc, 1, 8);
        if (p == 0) sout[r] = acc;
        __syncthreads();
    };
    stage(W1, s_v[0], s_v[1]);
    stage(W2, s_v[1], s_v[2]);
    stage(W3, s_v[2], s_v[3]);

    // broadcast codes[c] over shots (float4, coalesced)
    const float4* codes4 = (const float4*)s_v[3];
    float4* out4 = (float4*)out + (size_t)c * (KSHOT * REL / 4);
    const int n4 = (skip_tail && c == NWAY - 1) ? 40 * (REL / 4)   // rows 0..39
                                                : KSHOT * (REL / 4);
    for (int i = t; i < n4; i += 1024) out4[i] = codes4[i & 31];
}

// fallback patch: copy class-19 codes (row 0) into rows 40..49
__global__ __launch_bounds__(256) void leo_patch(float* out) {
    const int t = threadIdx.x;
    const float4* src = (const float4*)(out + (size_t)(NWAY - 1) * KSHOT * REL);
    float4* dst = (float4*)(out + ((size_t)(NWAY - 1) * KSHOT + 40) * REL);
    for (int i = t; i < 10 * (REL / 4); i += 256) dst[i] = src[i & 31];
}

// ---------------------------------------------------------------------------
extern "C" void kernel_launch(void* const* d_in, const int* in_sizes, int n_in,
                              void* d_out, int out_size, void* d_ws, size_t ws_size,
                              hipStream_t stream) {
    const float* support = (const float*)d_in[0];   // [1000][640]
    const float* W_enc   = (const float*)d_in[1];   // [64][640]
    const float* W1      = (const float*)d_in[2];   // [128][128]
    const float* W2      = (const float*)d_in[3];   // [128][128]
    const float* W3      = (const float*)d_in[4];   // [128][128]
    float* out = (float*)d_out;                     // [20][50][128]

    float* emb_ws;
    int skip_tail;
    if (ws_size >= (size_t)(NWAY * LAT) * sizeof(float)) {
        emb_ws = (float*)d_ws;                   skip_tail = 0;
    } else {
        emb_ws = out + OUT_FLOATS - NWAY * LAT;  skip_tail = 1;
    }

    leo_emb  <<<NWAY, 1024, 0, stream>>>(support, W_enc, emb_ws);
    leo_codes<<<NWAY, 1024, 0, stream>>>(emb_ws, W1, W2, W3, out, skip_tail);
    if (skip_tail) leo_patch<<<1, 256, 0, stream>>>(out);
}